// Round 3
// baseline (391.487 us; speedup 1.0000x reference)
//
#include <hip/hip_runtime.h>
#include <hip/hip_bf16.h>
#include <hip/hip_fp8.h>

#define MDIM 8192
#define KDIM 64

typedef __attribute__((ext_vector_type(8))) short bf16x8;
typedef __attribute__((ext_vector_type(4))) float f32x4;

__device__ __forceinline__ unsigned short bfbits(float f) {
    __hip_bfloat16 h = __float2bfloat16(f);   // RNE
    unsigned short u;
    __builtin_memcpy(&u, &h, 2);
    return u;
}

__device__ __forceinline__ unsigned char fp8bits(float f) {
    __hip_fp8_e4m3 h(f);                      // OCP e4m3fn, RNE (HW cvt on gfx950)
    unsigned char u;
    __builtin_memcpy(&u, &h, 1);
    return u;
}

__device__ __forceinline__ float fp8dec(unsigned char b) {
    __hip_fp8_e4m3 h;
    __builtin_memcpy(&h, &b, 1);
    return (float)h;
}

// ---------------- Pass 1: exact fp32 row sums of W (+ optional fp8 compress)
// + fused Yn = Y/sqrt(D) (bf16) and sq = ||Yn||^2 (fp32). One block per row. --
template<bool COMPRESS>
__global__ __launch_bounds__(256) void k_pass1(const float* __restrict__ W,
                                               const float* __restrict__ Y,
                                               unsigned char* __restrict__ W8,
                                               unsigned short* __restrict__ Ynb,
                                               float* __restrict__ sq) {
    const int row = blockIdx.x;
    const float4* Wr = (const float4*)(W + (size_t)row * MDIM);
    uchar4* W8r = (uchar4*)(W8 + (size_t)row * MDIM);   // never deref'd if !COMPRESS
    float s = 0.f;
#pragma unroll
    for (int c = 0; c < 8; ++c) {
        const int idx = threadIdx.x + 256 * c;
        float4 v = Wr[idx];
        s += (v.x + v.y) + (v.z + v.w);
        if (COMPRESS)
            W8r[idx] = make_uchar4(fp8bits(v.x), fp8bits(v.y), fp8bits(v.z), fp8bits(v.w));
    }
#pragma unroll
    for (int o = 32; o; o >>= 1) s += __shfl_down(s, o);
    __shared__ float part[4];
    if ((threadIdx.x & 63) == 0) part[threadIdx.x >> 6] = s;
    __syncthreads();
    const float tot = (part[0] + part[1]) + (part[2] + part[3]);  // D[row], exact fp32
    if (threadIdx.x < KDIM) {  // lanes 0..63 = wave 0
        const float yv = Y[(size_t)row * KDIM + threadIdx.x] / sqrtf(tot);
        Ynb[(size_t)row * KDIM + threadIdx.x] = bfbits(yv);
        float q = yv * yv;   // sq from unrounded fp32 value (matches reference)
#pragma unroll
        for (int o = 32; o; o >>= 1) q += __shfl_down(q, o);
        if (threadIdx.x == 0) sq[row] = q;
    }
}

// ---------------- Pass 2: fused G = Yn Yn^T (MFMA) + relu + W-weighted sum.
// 128x128 tile per block, 4 waves in 2x2, each wave 64x64 via 4x4 tiles of
// mfma_f32_16x16x32_bf16 (K=64 -> 2 K-steps). WMODE: 0 = fp32 W, 1 = fp8 W8.
template<int WMODE>
__global__ __launch_bounds__(256) void k_loss(const float* __restrict__ W,
                                              const unsigned char* __restrict__ W8,
                                              const unsigned short* __restrict__ Ynb,
                                              const float* __restrict__ sq,
                                              double* __restrict__ partials) {
    __shared__ unsigned short ldsI[128 * 64];
    __shared__ unsigned short ldsJ[128 * 64];
    __shared__ float sI[128], sJ[128];
    __shared__ float red[4];

    const int tid = threadIdx.x;
    const int i0 = blockIdx.y * 128;
    const int j0 = blockIdx.x * 128;

    // Stage Yn tiles into LDS with XOR swizzle (row stride 128 B would be a
    // 16-way bank conflict on ds_read_b128; byte ^= (row&7)<<4 fixes it, G4).
    {
        const uint4* gI = (const uint4*)(Ynb + (size_t)i0 * KDIM);
        const uint4* gJ = (const uint4*)(Ynb + (size_t)j0 * KDIM);
#pragma unroll
        for (int t = 0; t < 4; ++t) {
            int u = tid + 256 * t;           // 1024 uint4 per tile
            int row = u >> 3;                // 8 uint4 per row
            int kb  = (u & 7) << 4;          // byte offset in row
            int b = ((row << 7) + kb) ^ ((row & 7) << 4);
            *(uint4*)((char*)ldsI + b) = gI[u];
            *(uint4*)((char*)ldsJ + b) = gJ[u];
        }
        if (tid < 128) sI[tid] = sq[i0 + tid];
        else           sJ[tid - 128] = sq[j0 + (tid - 128)];
    }
    __syncthreads();

    const int lane = tid & 63;
    const int wid  = tid >> 6;   // 0..3
    const int wr   = wid >> 1;   // wave row (i) 0..1
    const int wc   = wid & 1;    // wave col (j) 0..1
    const int lr   = lane & 15;  // A-row / B-col within 16x16 tile
    const int lk   = lane >> 4;  // k-group 0..3

    f32x4 acc[4][4] = {};

#pragma unroll
    for (int ks = 0; ks < 2; ++ks) {
        const int kb = ks * 64 + lk * 16;   // byte offset of this lane's 8 bf16 k's
        bf16x8 af[4], bfr[4];
#pragma unroll
        for (int mi = 0; mi < 4; ++mi) {
            int r = wr * 64 + mi * 16 + lr;
            int b = ((r << 7) + kb) ^ ((r & 7) << 4);
            af[mi] = *(const bf16x8*)((const char*)ldsI + b);
        }
#pragma unroll
        for (int nj = 0; nj < 4; ++nj) {
            int r = wc * 64 + nj * 16 + lr;
            int b = ((r << 7) + kb) ^ ((r & 7) << 4);
            bfr[nj] = *(const bf16x8*)((const char*)ldsJ + b);
        }
#pragma unroll
        for (int mi = 0; mi < 4; ++mi)
#pragma unroll
            for (int nj = 0; nj < 4; ++nj)
                acc[mi][nj] = __builtin_amdgcn_mfma_f32_16x16x32_bf16(
                    af[mi], bfr[nj], acc[mi][nj], 0, 0, 0);
    }

    // Epilogue. C/D layout (m89-verified): col = lane&15, row = (lane>>4)*4 + reg.
    float lsum = 0.f;
#pragma unroll
    for (int mi = 0; mi < 4; ++mi) {
        const int ib = wr * 64 + mi * 16 + lk * 4;
#pragma unroll
        for (int nj = 0; nj < 4; ++nj) {
            const int jb = wc * 64 + nj * 16 + lr;
            const float sqj = sJ[jb];
            const size_t off = (size_t)(i0 + ib) * MDIM + (j0 + jb);
#pragma unroll
            for (int reg = 0; reg < 4; ++reg) {
                float w;
                if (WMODE == 1) w = fp8dec(W8[off + (size_t)reg * MDIM]);
                else            w = W[off + (size_t)reg * MDIM];
                float d2 = fmaxf(sI[ib + reg] + sqj - 2.0f * acc[mi][nj][reg], 0.f);
                lsum += w * d2;
            }
        }
    }

#pragma unroll
    for (int o = 32; o; o >>= 1) lsum += __shfl_down(lsum, o);
    if (lane == 0) red[wid] = lsum;
    __syncthreads();
    if (tid == 0) {
        double t = (double)red[0] + (double)red[1] + (double)red[2] + (double)red[3];
        partials[blockIdx.y * 64 + blockIdx.x] = t;
    }
}

// ---------------- Finalize: reduce 4096 partials, scale, write scalar -------
__global__ __launch_bounds__(256) void k_final(const double* __restrict__ partials,
                                               float* __restrict__ out) {
    double s = 0.0;
#pragma unroll
    for (int i = 0; i < 16; ++i) s += partials[threadIdx.x + 256 * i];
#pragma unroll
    for (int o = 32; o; o >>= 1) s += __shfl_down(s, o);
    __shared__ double part[4];
    if ((threadIdx.x & 63) == 0) part[threadIdx.x >> 6] = s;
    __syncthreads();
    if (threadIdx.x == 0) {
        double t = (part[0] + part[1]) + (part[2] + part[3]);
        out[0] = (float)(t * (1.0 / (2.0 * (double)MDIM)));
    }
}

extern "C" void kernel_launch(void* const* d_in, const int* in_sizes, int n_in,
                              void* d_out, int out_size, void* d_ws, size_t ws_size,
                              hipStream_t stream) {
    const float* W = (const float*)d_in[0];
    const float* Y = (const float*)d_in[1];
    float* out = (float*)d_out;

    char* ws = (char*)d_ws;
    float*  sq       = (float*)(ws);                          // 32 KiB
    double* partials = (double*)(ws + 32 * 1024);             // 32 KiB
    unsigned short* Ynb = (unsigned short*)(ws + 64 * 1024);  // 1 MiB
    unsigned char*  W8  = (unsigned char*)(ws + (2ull << 20)); // 64 MiB

    const size_t need = (2ull << 20) + (size_t)MDIM * MDIM;    // 66 MiB
    const bool compress = ws_size >= need;

    if (compress) {
        k_pass1<true><<<dim3(MDIM), dim3(256), 0, stream>>>(W, Y, W8, Ynb, sq);
        k_loss<1><<<dim3(64, 64), dim3(256), 0, stream>>>(W, W8, Ynb, sq, partials);
    } else {
        k_pass1<false><<<dim3(MDIM), dim3(256), 0, stream>>>(W, Y, W8, Ynb, sq);
        k_loss<0><<<dim3(64, 64), dim3(256), 0, stream>>>(W, W8, Ynb, sq, partials);
    }
    k_final<<<1, 256, 0, stream>>>(partials, out);
}